// Round 4
// baseline (23178.700 us; speedup 1.0000x reference)
//
#include <hip/hip_runtime.h>
#include <hip/hip_bf16.h>

// AWD-LSTM forward, T=1024 B=64 DIN=512 H=1024.
// Inputs fp32 (reference dtype; R1-NaN + R2-garbage triangulate this),
// OUTPUT fp32 (reference dtype — R2/R3 failed by writing bf16 into float*).
// Round 4: fp32 out; bf16 h double-buffer in ws; rest identical to R3.

#define TT   1024
#define BB   64
#define DIN_ 512
#define HH   1024

typedef __attribute__((ext_vector_type(8))) short  short8;   // 8 bf16
typedef __attribute__((ext_vector_type(4))) float  floatx4;

__device__ __forceinline__ unsigned short f2bf(float f) {
    unsigned u = __builtin_bit_cast(unsigned, f);
    unsigned r = u + 0x7FFFu + ((u >> 16) & 1u);   // RNE
    return (unsigned short)(r >> 16);
}
__device__ __forceinline__ float b2f(unsigned short u) {
    return __builtin_bit_cast(float, (unsigned)u << 16);
}
// 8 consecutive fp32 -> bf16 MFMA fragment
__device__ __forceinline__ short8 frag_f32(const float* __restrict__ p) {
    floatx4 f0 = *(const floatx4*)p;
    floatx4 f1 = *(const floatx4*)(p + 4);
    short8 a;
#pragma unroll
    for (int e = 0; e < 4; ++e) {
        a[e]     = (short)f2bf(f0[e]);
        a[e + 4] = (short)f2bf(f1[e]);
    }
    return a;
}

// ---- ws layout (bytes) ----  total ~520 KB
#define WS_FLAG  0        // int: 1 = inputs bf16, 0 = fp32
#define WS_CWS   1024     // float c_ws[65536]
#define WS_HBUF  263168   // ushort hbuf[2][65536] (bf16 h state, double-buffered)

// Probe first 256 ushorts of Wi (uniform(+-2^-5)): bf16 -> ~100% exponent in
// [0x60,0x7B]; fp32-as-ushort -> ~55% (low mantissa halves are random bits).
__global__ __launch_bounds__(64) void dtype_probe(const unsigned short* __restrict__ wi_raw,
                                                  int* __restrict__ flag) {
    int lane = threadIdx.x;
    int pass = 0;
#pragma unroll
    for (int k = 0; k < 4; ++k) {
        unsigned e = (wi_raw[lane * 4 + k] >> 7) & 0xFF;
        pass += (e >= 0x60 && e <= 0x7B) ? 1 : 0;
    }
    for (int off = 32; off > 0; off >>= 1) pass += __shfl_down(pass, off);
    if (lane == 0) *flag = (pass >= 200) ? 1 : 0;
}

__global__ __launch_bounds__(256) void lstm_init(
    const void* __restrict__ h0, const void* __restrict__ c0,
    const int* __restrict__ flag,
    unsigned short* __restrict__ hbuf0, float* __restrict__ c_ws)
{
    const bool isbf = (*flag != 0);
    int i = blockIdx.x * 256 + threadIdx.x;   // 256*256 = 65536 = B*H
    hbuf0[i] = isbf ? ((const unsigned short*)h0)[i] : f2bf(((const float*)h0)[i]);
    c_ws[i]  = isbf ? b2f(((const unsigned short*)c0)[i]) : ((const float*)c0)[i];
}

// One timestep. Block covers jb = blockIdx.x*4 (4 h-cols x 4 gates = 16 cols).
// preact[64x16] = keep*(h @ Wh^T) + x_t @ Wi^T  via mfma_f32_16x16x32_bf16.
__global__ __launch_bounds__(256) void lstm_step(
    const void* __restrict__ x,      // [T,B,DIN] fp32 (or bf16 per probe)
    const void* __restrict__ Wi,     // [4H,DIN]
    const void* __restrict__ bi,     // [4H]
    const void* __restrict__ Wh,     // [4H,H]
    const void* __restrict__ bh,     // [4H]
    const int* __restrict__ tok,     // [T,B]
    const int* __restrict__ flag,
    unsigned short* __restrict__ hbuf,  // [2][B*H] bf16 double buffer (ws)
    float* __restrict__ c_ws,           // [B*H] fp32 (ws)
    float* __restrict__ out,            // fp32: [T,B,H] ++ hT[B,H] ++ cT[B,H]
    int t)
{
    const int tid  = threadIdx.x;
    const int wave = tid >> 6;
    const int lane = tid & 63;
    const int jb   = blockIdx.x * 4;

    __shared__ float preact[64][17];

    // mfma_f32_16x16x32_bf16 lane maps (guide Sec.3, HW-verified):
    //   A: m = lane&15, k = (lane>>4)*8 + j     B: n = lane&15, same k
    //   D: col = lane&15, row = (lane>>4)*4 + r
    const int m    = lane & 15;
    const int colq = lane & 15;
    const int quad = lane >> 4;
    const int b_a  = wave * 16 + m;                       // batch row (A)
    const int wrow = (colq >> 2) * HH + jb + (colq & 3);  // weight row (B col n)

    const bool isbf = (*flag != 0);

    floatx4 acc = {0.f, 0.f, 0.f, 0.f};

    const unsigned short* hsrc = hbuf + (t & 1) * (BB * HH);  // state entering step t

    // ---- K part 1: h @ Wh^T (k = 0..1023); A always bf16 ----
    {
        const unsigned short* ap = hsrc + b_a * HH + quad * 8;
        if (isbf) {
            const unsigned short* bp = (const unsigned short*)Wh + wrow * HH + quad * 8;
#pragma unroll 8
            for (int ki = 0; ki < 32; ++ki) {
                short8 a = *(const short8*)(ap + ki * 32);
                short8 b = *(const short8*)(bp + ki * 32);
                acc = __builtin_amdgcn_mfma_f32_16x16x32_bf16(a, b, acc, 0, 0, 0);
            }
        } else {
            const float* bp = (const float*)Wh + wrow * HH + quad * 8;
#pragma unroll 4
            for (int ki = 0; ki < 32; ++ki) {
                short8 a = *(const short8*)(ap + ki * 32);
                short8 b = frag_f32(bp + ki * 32);
                acc = __builtin_amdgcn_mfma_f32_16x16x32_bf16(a, b, acc, 0, 0, 0);
            }
        }
    }

    // ---- reset at consumption: keep*(h@Wh^T) — zero rows where reset ----
    // reference: at step t, reset iff t>1 && input_tokens[t-1]==RESET_ID(0)
    if (t > 1) {
#pragma unroll
        for (int r = 0; r < 4; ++r) {
            int bb = wave * 16 + quad * 4 + r;           // D row -> batch
            if (tok[(t - 1) * BB + bb] == 0) acc[r] = 0.f;
        }
    }

    // ---- K part 2: x_t @ Wi^T (k = 0..511) ----
    if (isbf) {
        const unsigned short* ap =
            (const unsigned short*)x + (size_t)t * BB * DIN_ + b_a * DIN_ + quad * 8;
        const unsigned short* bp = (const unsigned short*)Wi + wrow * DIN_ + quad * 8;
#pragma unroll 8
        for (int ki = 0; ki < 16; ++ki) {
            short8 a = *(const short8*)(ap + ki * 32);
            short8 b = *(const short8*)(bp + ki * 32);
            acc = __builtin_amdgcn_mfma_f32_16x16x32_bf16(a, b, acc, 0, 0, 0);
        }
    } else {
        const float* ap = (const float*)x + (size_t)t * BB * DIN_ + b_a * DIN_ + quad * 8;
        const float* bp = (const float*)Wi + wrow * DIN_ + quad * 8;
#pragma unroll 4
        for (int ki = 0; ki < 16; ++ki) {
            short8 a = frag_f32(ap + ki * 32);
            short8 b = frag_f32(bp + ki * 32);
            acc = __builtin_amdgcn_mfma_f32_16x16x32_bf16(a, b, acc, 0, 0, 0);
        }
    }

#pragma unroll
    for (int r = 0; r < 4; ++r)
        preact[wave * 16 + quad * 4 + r][colq] = acc[r];
    __syncthreads();

    // ---- cell epilogue: thread -> (b = tid>>2, jj = tid&3) ----
    const int b  = tid >> 2;
    const int jj = tid & 3;
    const int j  = jb + jj;

    float p[4];
#pragma unroll
    for (int q = 0; q < 4; ++q) {
        float vbi = isbf ? b2f(((const unsigned short*)bi)[q * HH + j])
                         : ((const float*)bi)[q * HH + j];
        float vbh = isbf ? b2f(((const unsigned short*)bh)[q * HH + j])
                         : ((const float*)bh)[q * HH + j];
        p[q] = preact[b][q * 4 + jj] + vbi + vbh;
    }
    float ig = 1.f / (1.f + __expf(-p[0]));
    float fg = 1.f / (1.f + __expf(-p[1]));
    float og = 1.f / (1.f + __expf(-p[2]));
    float gg = tanhf(p[3]);                    // g from LAST quarter (source quirk)

    float keep   = (t > 1 && tok[(t - 1) * BB + b] == 0) ? 0.f : 1.f;
    float c_prev = c_ws[b * HH + j] * keep;
    float c_t    = fg * c_prev + ig * gg;
    float h_t    = og * tanhf(c_t);

    out[(size_t)t * BB * HH + b * HH + j] = h_t;        // fp32 output!
    c_ws[b * HH + j] = c_t;                             // raw c (keep applied at read)

    // h state for step t+1 (pre-reset; reset applied at consumption)
    unsigned short* hn = hbuf + ((t + 1) & 1) * (BB * HH);
    hn[b * HH + j] = f2bf(h_t);

    if (t == TT - 1) {
        out[(size_t)TT * BB * HH + b * HH + j]           = h_t;  // hT fp32
        out[(size_t)TT * BB * HH + BB * HH + b * HH + j] = c_t;  // cT fp32
    }
}

extern "C" void kernel_launch(void* const* d_in, const int* in_sizes, int n_in,
                              void* d_out, int out_size, void* d_ws, size_t ws_size,
                              hipStream_t stream) {
    const void* x  = d_in[0];
    const void* h0 = d_in[1];
    const void* c0 = d_in[2];
    const void* Wi = d_in[3];
    const void* bi = d_in[4];
    const void* Wh = d_in[5];
    const void* bh = d_in[6];
    const int* tok = (const int*)d_in[7];
    float* out = (float*)d_out;

    char* ws = (char*)d_ws;
    int*            flag = (int*)(ws + WS_FLAG);
    float*          c_ws = (float*)(ws + WS_CWS);
    unsigned short* hbuf = (unsigned short*)(ws + WS_HBUF);

    dtype_probe<<<1, 64, 0, stream>>>((const unsigned short*)Wi, flag);
    lstm_init<<<256, 256, 0, stream>>>(h0, c0, flag, hbuf, c_ws);
    for (int t = 0; t < TT; ++t) {
        lstm_step<<<256, 256, 0, stream>>>(x, Wi, bi, Wh, bh, tok, flag,
                                           hbuf, c_ws, out, t);
    }
}